// Round 7
// baseline (515.657 us; speedup 1.0000x reference)
//
#include <hip/hip_runtime.h>
#include <hip/hip_bf16.h>
#include <cstdint>

// TGAT fused pipeline for MI355X — round 7: bf16 q/kv gathers (halve the
// random-fetch bytes that bound k3 at the ~2.25 TB/s fabric mix ceiling).
// Stages:
//   k1: h1pre = x @ Wlin + blin                        [N,32]  (16 rows/blk)
//   k2: node encoders + gated combine; writes q (bf16), k|v packed (bf16),
//       skip (f32)
//   k3: edge kernel — MFMA edge features + attention; bf16 gathers;
//       exp(alpha)*(v+e) via global_atomic_pk_add_bf16, den via 2 fp32 atomics
//   k4: h2 = agg(bf16)/den + skip; out = log_softmax(h2 @ Wout + bout)
//
// Workspace: qbh bf16 (6.4MB) | kvb bf16 (12.8MB) | skipb f32 (12.8MB) |
//            h1pre f32 (12.8MB) | agg bf16 (6.4MB) | den f32 (0.8MB) ~= 52MB

#define FIN 172
#define INV_SQRT_C 0.25f

typedef _Float16 f16x8 __attribute__((ext_vector_type(8)));
typedef float f32x4 __attribute__((ext_vector_type(4)));

// v_cvt_pk_bf16_f32: dst[15:0]=bf16(lo), dst[31:16]=bf16(hi), RNE.
__device__ __forceinline__ uint32_t cvt_pk_bf16(float lo, float hi) {
    uint32_t r;
    asm("v_cvt_pk_bf16_f32 %0, %1, %2" : "=v"(r) : "v"(lo), "v"(hi));
    return r;
}

__device__ __forceinline__ float bf2f(unsigned short u) {
    union { uint32_t i; float f; } x;
    x.i = ((uint32_t)u) << 16;
    return x.f;
}

// Fire-and-forget packed bf16 atomic add (2 channels / 4 bytes per op).
__device__ __forceinline__ void pk_atomic_add_bf16(void* addr, uint32_t data) {
    asm volatile("global_atomic_pk_add_bf16 %0, %1, off"
                 :: "v"((uint64_t)(uintptr_t)addr), "v"(data) : "memory");
}

// ---------------------------------------------------------------------------
// k1: h1pre = x @ Wlin + blin.  256 threads = 8 thread-rows x 32 out-cols,
// each thread computes 2 rows (r, r+8) -> 16 rows/block; W LDS reads shared.
// ---------------------------------------------------------------------------
__global__ __launch_bounds__(256) void k1_lin(
    const float* __restrict__ x, const float* __restrict__ Wlin,
    const float* __restrict__ blin, float* __restrict__ h1pre, int n)
{
    __shared__ __align__(16) float WlT[32][174];   // [out][k], padded
    __shared__ __align__(16) float xs[16][FIN];
    const int t = threadIdx.x;

    for (int i = t; i < FIN * 32; i += 256) {
        int kk = i >> 5, o = i & 31;               // Wlin row-major [k][o]
        WlT[o][kk] = Wlin[i];
    }
    const int row0 = blockIdx.x * 16;
    for (int i = t; i < 16 * FIN; i += 256) {
        int rr = i / FIN, kk = i - rr * FIN;
        int gr = row0 + rr;
        xs[rr][kk] = (gr < n) ? x[(size_t)gr * FIN + kk] : 0.f;
    }
    __syncthreads();

    const int o = t & 31, r = t >> 5;
    float acc0 = blin[o], acc1 = acc0;
    const float2* wp  = reinterpret_cast<const float2*>(&WlT[o][0]);
    const float2* xp0 = reinterpret_cast<const float2*>(&xs[r][0]);
    const float2* xp1 = reinterpret_cast<const float2*>(&xs[r + 8][0]);
    #pragma unroll 4
    for (int kk = 0; kk < FIN / 2; ++kk) {
        float2 wv = wp[kk], xa = xp0[kk], xb = xp1[kk];
        acc0 = fmaf(xa.x, wv.x, acc0);
        acc0 = fmaf(xa.y, wv.y, acc0);
        acc1 = fmaf(xb.x, wv.x, acc1);
        acc1 = fmaf(xb.y, wv.y, acc1);
    }
    const int g0 = row0 + r, g1 = row0 + r + 8;
    if (g0 < n) h1pre[(size_t)g0 * 32 + o] = acc0;
    if (g1 < n) h1pre[(size_t)g1 * 32 + o] = acc1;
}

// ---------------------------------------------------------------------------
// Small matvec helper: out[o] = B[o] + sum_k v[k] * W[k*O + o]. W/B in LDS.
// ---------------------------------------------------------------------------
template <int K, int O>
__device__ __forceinline__ void matvecKO(const float* __restrict__ v,
                                         const float* __restrict__ W,
                                         const float* __restrict__ B,
                                         float* __restrict__ out)
{
    #pragma unroll
    for (int o4 = 0; o4 < O / 4; ++o4) {
        float a0 = B[o4 * 4 + 0], a1 = B[o4 * 4 + 1];
        float a2 = B[o4 * 4 + 2], a3 = B[o4 * 4 + 3];
        #pragma unroll
        for (int k = 0; k < K; ++k) {
            float4 wv = *reinterpret_cast<const float4*>(&W[k * O + o4 * 4]);
            float hv = v[k];
            a0 = fmaf(hv, wv.x, a0);
            a1 = fmaf(hv, wv.y, a1);
            a2 = fmaf(hv, wv.z, a2);
            a3 = fmaf(hv, wv.w, a3);
        }
        out[o4 * 4 + 0] = a0; out[o4 * 4 + 1] = a1;
        out[o4 * 4 + 2] = a2; out[o4 * 4 + 3] = a3;
    }
}

__device__ __forceinline__ void store32(float* __restrict__ dst,
                                        const float* __restrict__ v)
{
    float4* d4 = reinterpret_cast<float4*>(dst);
    #pragma unroll
    for (int i = 0; i < 8; ++i)
        d4[i] = make_float4(v[4 * i], v[4 * i + 1], v[4 * i + 2], v[4 * i + 3]);
}

// ---------------------------------------------------------------------------
// k2: per-node encoder + combine + projections. One thread per node.
// q -> bf16 [N,32]; k|v -> packed bf16 [N,64] ({k0..k31, v0..v31}); skip f32.
// ---------------------------------------------------------------------------
__global__ __launch_bounds__(256) void k2_enc(
    const float* __restrict__ h1pre,
    const float* __restrict__ node_interval, const float* __restrict__ node_degree,
    const float* __restrict__ Wtf, const float* __restrict__ btf,
    const float* __restrict__ Wd,  const float* __restrict__ bd,
    const float* __restrict__ Wenc, const float* __restrict__ benc,
    const float* __restrict__ Wx,  const float* __restrict__ bx,
    const float* __restrict__ Wcomb, const float* __restrict__ bcomb,
    const float* __restrict__ Wq,  const float* __restrict__ bq,
    const float* __restrict__ Wk,  const float* __restrict__ bk,
    const float* __restrict__ Wv,  const float* __restrict__ bv,
    const float* __restrict__ Wskip, const float* __restrict__ bskip,
    uint32_t* __restrict__ q32, uint32_t* __restrict__ kv32,
    float* __restrict__ skipb, int n)
{
    __shared__ __align__(16) float sWenc[64], sWx[256], sWcomb[1280];
    __shared__ __align__(16) float sWq[1024], sWk[1024], sWv[1024], sWs[1024];
    __shared__ float sWtf[8], sbtf[8], sWd[8], sbd[8], sbenc[8], sbx[8];
    __shared__ float sbcomb[32], sbq[32], sbk[32], sbv[32], sbs[32];

    const int t = threadIdx.x;
    if (t < 8) {
        sWtf[t] = Wtf[t]; sbtf[t] = btf[t];
        sWd[t]  = Wd[t];  sbd[t]  = bd[t];
        sbenc[t] = benc[t]; sbx[t] = bx[t];
    }
    if (t < 32) {
        sbcomb[t] = bcomb[t]; sbq[t] = bq[t]; sbk[t] = bk[t];
        sbv[t] = bv[t]; sbs[t] = bskip[t];
    }
    if (t < 64) sWenc[t] = Wenc[t];
    if (t < 256) sWx[t] = Wx[t];
    for (int i = t; i < 1280; i += 256) sWcomb[i] = Wcomb[i];
    for (int i = t; i < 1024; i += 256) {
        sWq[i] = Wq[i]; sWk[i] = Wk[i]; sWv[i] = Wv[i]; sWs[i] = Wskip[i];
    }
    __syncthreads();

    const int nid = blockIdx.x * 256 + t;
    if (nid >= n) return;

    float h1p[32];
    {
        const float2* hp = reinterpret_cast<const float2*>(h1pre + (size_t)nid * 32);
        #pragma unroll
        for (int i = 0; i < 16; ++i) {
            float2 v2 = hp[i];
            h1p[2 * i] = v2.x; h1p[2 * i + 1] = v2.y;
        }
    }
    const float ti = node_interval[nid], dg = node_degree[nid];
    float tf[8], de[8];
    #pragma unroll
    for (int j = 0; j < 8; ++j) {
        tf[j] = fmaf(ti, sWtf[j], sbtf[j]);
        de[j] = fmaf(dg, sWd[j], sbd[j]);
    }
    float xp[8];
    matvecKO<32, 8>(h1p, sWx, sbx, xp);
    #pragma unroll
    for (int o = 0; o < 8; ++o) xp[o] = tanhf(xp[o]);

    float ep0[8], ep1[8];
    matvecKO<8, 8>(tf, sWenc, sbenc, ep0);
    matvecKO<8, 8>(de, sWenc, sbenc, ep1);
    float sc0 = 0.f, sc1 = 0.f;
    #pragma unroll
    for (int o = 0; o < 8; ++o) {
        sc0 = fmaf(tanhf(ep0[o]), xp[o], sc0);
        sc1 = fmaf(tanhf(ep1[o]), xp[o], sc1);
    }
    const float mm = fmaxf(sc0, sc1);
    const float e0 = __expf(sc0 - mm), e1 = __expf(sc1 - mm);
    const float inv = 1.f / (e0 + e1);
    const float s0 = e0 * inv, s1 = e1 * inv;

    float v40[40];
    #pragma unroll
    for (int i = 0; i < 32; ++i) v40[i] = h1p[i];
    #pragma unroll
    for (int j = 0; j < 8; ++j) v40[32 + j] = fmaf(s0, tf[j], s1 * de[j]);
    float h1[32];
    matvecKO<40, 32>(v40, sWcomb, sbcomb, h1);

    float tq[32], tk[32], tv[32], ts[32];
    matvecKO<32, 32>(h1, sWq, sbq, tq);
    matvecKO<32, 32>(h1, sWk, sbk, tk);
    matvecKO<32, 32>(h1, sWv, sbv, tv);
    matvecKO<32, 32>(h1, sWs, sbs, ts);

    uint32_t* qw  = q32  + (size_t)nid * 16;
    uint32_t* kvw = kv32 + (size_t)nid * 32;
    #pragma unroll
    for (int p = 0; p < 16; ++p) {
        qw[p]       = cvt_pk_bf16(tq[2 * p], tq[2 * p + 1]);
        kvw[p]      = cvt_pk_bf16(tk[2 * p], tk[2 * p + 1]);
        kvw[16 + p] = cvt_pk_bf16(tv[2 * p], tv[2 * p + 1]);
    }
    store32(skipb + (size_t)nid * 32, ts);
}

// ---------------------------------------------------------------------------
// k3: edge kernel. One wave = one 16-edge tile (grid-stride persistent).
// Two mfma_f32_16x16x32_f16 compute the 16x32 edge-feature tile.
// bf16 gathers: q[dst] = 1 line (64B), k|v[src] packed = 2 lines (128B).
// Output: 16 packed-bf16 atomics + 2 fp32 den atomics per edge.
// ---------------------------------------------------------------------------
__global__ __launch_bounds__(256) void k3_edge(
    const int* __restrict__ ei, const float* __restrict__ node_time,
    const float* __restrict__ edge_time,
    const unsigned short* __restrict__ qbh, const unsigned short* __restrict__ kvb,
    const float* __restrict__ Wt, const float* __restrict__ bt,
    const float* __restrict__ We, const float* __restrict__ be,
    unsigned short* __restrict__ agg, float* __restrict__ den,
    int numE, int nTiles)
{
    const int lane = threadIdx.x & 63;
    const int g = lane >> 4;          // k-group / C row group
    const int m = lane & 15;          // A row (edge-in-tile) / B,C column

    // Per-thread constants (amortized over the grid-stride loop).
    float wtr[8], btr[8];
    f16x8 B0, B1;
    #pragma unroll
    for (int i = 0; i < 8; ++i) {
        const int k = g * 8 + i;
        wtr[i] = Wt[k];
        btr[i] = bt[k];
        B0[i] = (_Float16)We[k * 32 + m];
        B1[i] = (_Float16)We[k * 32 + 16 + m];
    }
    const float be0 = be[m], be1 = be[16 + m];

    const int wid    = blockIdx.x * (blockDim.x >> 6) + (threadIdx.x >> 6);
    const int nWaves = gridDim.x * (blockDim.x >> 6);

    for (int tile = wid; tile < nTiles; tile += nWaves) {
        const int e0 = tile * 16;
        const int eA = e0 + m;                     // edge whose metadata this lane owns
        int srcm = 0, dstm = 0;
        float rel = 0.f;
        if (eA < numE) {
            srcm = ei[eA];
            dstm = ei[numE + eA];
            rel  = node_time[srcm] - edge_time[eA];
        }

        // A fragment: ct[k] for edge row m, k = 8g+i.
        f16x8 A;
        #pragma unroll
        for (int i = 0; i < 8; ++i)
            A[i] = (_Float16)__cosf(fmaf(rel, wtr[i], btr[i]));

        f32x4 acc0 = {0.f, 0.f, 0.f, 0.f};
        f32x4 acc1 = {0.f, 0.f, 0.f, 0.f};
        acc0 = __builtin_amdgcn_mfma_f32_16x16x32_f16(A, B0, acc0, 0, 0, 0);
        acc1 = __builtin_amdgcn_mfma_f32_16x16x32_f16(A, B1, acc1, 0, 0, 0);

        #pragma unroll
        for (int r = 0; r < 4; ++r) {
            const int j = g * 4 + r;               // edge-in-tile this reg row holds
            const int e = e0 + j;
            if (e < numE) {
                const int srcr = __shfl(srcm, j);  // lane j owns edge e0+j's metadata
                const int dstr = __shfl(dstm, j);

                const float ef0 = acc0[r] + be0;   // channel m      (head 0)
                const float ef1 = acc1[r] + be1;   // channel 16+m   (head 1)

                const unsigned short* qs  = qbh + (size_t)dstr * 32;
                const unsigned short* kvs = kvb + (size_t)srcr * 64;
                const float q0 = bf2f(qs[m]),       q1 = bf2f(qs[16 + m]);
                const float k0 = bf2f(kvs[m]),      k1 = bf2f(kvs[16 + m]);
                const float v0 = bf2f(kvs[32 + m]), v1 = bf2f(kvs[48 + m]);

                float p0 = q0 * (k0 + ef0);
                float p1 = q1 * (k1 + ef1);
                #pragma unroll
                for (int s = 1; s < 16; s <<= 1) { // reduce over the 16 channels
                    p0 += __shfl_xor(p0, s);
                    p1 += __shfl_xor(p1, s);
                }
                const float w0 = __expf(p0 * INV_SQRT_C);
                const float w1 = __expf(p1 * INV_SQRT_C);

                const float t0 = w0 * (v0 + ef0);  // contribution to ch m
                const float t1 = w1 * (v1 + ef1);  // contribution to ch 16+m
                const float x0 = __shfl_xor(t0, 1);
                const float x1 = __shfl_xor(t1, 1);
                // even lane m: pair (m, m+1) from head-0 values
                // odd  lane m: pair (15+m, 16+m) from head-1 values
                const uint32_t dE = cvt_pk_bf16(t0, x0);
                const uint32_t dO = cvt_pk_bf16(x1, t1);
                const uint32_t data = (m & 1) ? dO : dE;
                const int choff = (m & 1) ? (15 + m) : m;
                const size_t db = (size_t)dstr * 32;
                pk_atomic_add_bf16(agg + db + choff, data);

                if (m < 2) atomicAdd(&den[(size_t)dstr * 2 + m], m ? w1 : w0);
            }
        }
    }
}

// ---------------------------------------------------------------------------
// k4: h2 = agg(bf16)/den + skip; out = log_softmax(h2 @ Wout + bout).
// ---------------------------------------------------------------------------
__global__ __launch_bounds__(256) void k4_out(
    const unsigned short* __restrict__ agg, const float* __restrict__ den,
    const float* __restrict__ skipb,
    const float* __restrict__ Wout, const float* __restrict__ bout,
    float* __restrict__ out, int n)
{
    __shared__ float sW[64];
    __shared__ float sb[2];
    const int t = threadIdx.x;
    if (t < 64) sW[t] = Wout[t];
    if (t < 2) sb[t] = bout[t];
    __syncthreads();

    const int nid = blockIdx.x * 256 + t;
    if (nid >= n) return;

    const float inv0 = 1.f / (den[(size_t)nid * 2 + 0] + 1e-16f);
    const float inv1 = 1.f / (den[(size_t)nid * 2 + 1] + 1e-16f);
    const uint32_t* ag = reinterpret_cast<const uint32_t*>(agg) + (size_t)nid * 16;
    const float*    sk = skipb + (size_t)nid * 32;

    float o0 = sb[0], o1 = sb[1];
    #pragma unroll
    for (int p = 0; p < 16; ++p) {                 // channel pair (2p, 2p+1)
        const uint32_t u = ag[p];
        const float aLo = __uint_as_float(u << 16);
        const float aHi = __uint_as_float(u & 0xFFFF0000u);
        const float iv = (p < 8) ? inv0 : inv1;
        const float hLo = fmaf(aLo, iv, sk[2 * p]);
        const float hHi = fmaf(aHi, iv, sk[2 * p + 1]);
        o0 = fmaf(hLo, sW[(2 * p) * 2],     o0);
        o1 = fmaf(hLo, sW[(2 * p) * 2 + 1], o1);
        o0 = fmaf(hHi, sW[(2 * p + 1) * 2],     o0);
        o1 = fmaf(hHi, sW[(2 * p + 1) * 2 + 1], o1);
    }
    const float mm = fmaxf(o0, o1);
    const float lse = mm + __logf(__expf(o0 - mm) + __expf(o1 - mm));
    out[(size_t)nid * 2 + 0] = o0 - lse;
    out[(size_t)nid * 2 + 1] = o1 - lse;
}

// ---------------------------------------------------------------------------
extern "C" void kernel_launch(void* const* d_in, const int* in_sizes, int n_in,
                              void* d_out, int out_size, void* d_ws, size_t ws_size,
                              hipStream_t stream)
{
    const float* x             = (const float*)d_in[0];
    const int*   ei            = (const int*)  d_in[1];
    const float* node_time     = (const float*)d_in[2];
    const float* edge_time     = (const float*)d_in[3];
    const float* node_interval = (const float*)d_in[4];
    const float* node_degree   = (const float*)d_in[5];
    const float* Wt    = (const float*)d_in[6];  const float* bt    = (const float*)d_in[7];
    const float* Wd    = (const float*)d_in[8];  const float* bd    = (const float*)d_in[9];
    const float* Wtf   = (const float*)d_in[10]; const float* btf   = (const float*)d_in[11];
    const float* Wenc  = (const float*)d_in[12]; const float* benc  = (const float*)d_in[13];
    const float* Wx    = (const float*)d_in[14]; const float* bx    = (const float*)d_in[15];
    const float* Wlin  = (const float*)d_in[16]; const float* blin  = (const float*)d_in[17];
    const float* Wcomb = (const float*)d_in[18]; const float* bcomb = (const float*)d_in[19];
    const float* Wq    = (const float*)d_in[20]; const float* bq    = (const float*)d_in[21];
    const float* Wk    = (const float*)d_in[22]; const float* bk    = (const float*)d_in[23];
    const float* Wv    = (const float*)d_in[24]; const float* bv    = (const float*)d_in[25];
    const float* We    = (const float*)d_in[26]; const float* be    = (const float*)d_in[27];
    const float* Wskip = (const float*)d_in[28]; const float* bskip = (const float*)d_in[29];
    const float* Wout  = (const float*)d_in[30]; const float* bout  = (const float*)d_in[31];

    const int n    = in_sizes[2];   // node_time: [N]
    const int numE = in_sizes[3];   // edge_time: [E,1]

    // ---- workspace carve (bytes) ----
    char* base = (char*)d_ws;
    unsigned short* qbh = (unsigned short*)base; base += (size_t)n * 32 * 2;
    unsigned short* kvb = (unsigned short*)base; base += (size_t)n * 64 * 2;
    float* skipb = (float*)base; base += (size_t)n * 32 * 4;
    float* h1pre = (float*)base; base += (size_t)n * 32 * 4;
    unsigned short* agg = (unsigned short*)base; base += (size_t)n * 32 * 2;
    float* den   = (float*)base; base += (size_t)n * 2 * 4;

    // zero the atomic accumulators (agg bf16 + den f32, contiguous)
    hipMemsetAsync(agg, 0, (size_t)n * (32 * 2 + 2 * 4), stream);

    k1_lin<<<(n + 15) / 16, 256, 0, stream>>>(x, Wlin, blin, h1pre, n);

    k2_enc<<<(n + 255) / 256, 256, 0, stream>>>(
        h1pre, node_interval, node_degree,
        Wtf, btf, Wd, bd, Wenc, benc, Wx, bx, Wcomb, bcomb,
        Wq, bq, Wk, bk, Wv, bv, Wskip, bskip,
        (uint32_t*)qbh, (uint32_t*)kvb, skipb, n);

    const int nTiles = (numE + 15) / 16;
    k3_edge<<<2048, 256, 0, stream>>>(
        ei, node_time, edge_time, qbh, kvb,
        Wt, bt, We, be, agg, den, numE, nTiles);

    k4_out<<<(n + 255) / 256, 256, 0, stream>>>(
        agg, den, skipb, Wout, bout, (float*)d_out, n);
}

// Round 8
// 492.388 us; speedup vs baseline: 1.0473x; 1.0473x over previous
//
#include <hip/hip_runtime.h>
#include <hip/hip_bf16.h>
#include <cstdint>

// TGAT fused pipeline for MI355X — round 8: latency-oriented k3.
//   * lane-interleaved bf16 layouts: q pair (1x4B load), kv quad (1x8B load)
//   * all gathers issued up-front per tile; next tile's stage-1 prefetched
//   * den packed into one pk-bf16 atomic (17 atomic ops/edge)
// Stages:
//   k1: h1pre = x @ Wlin + blin                        [N,32]
//   k2: encoders + combine; q/kv interleaved bf16, skip f32
//   k3: edge kernel — MFMA edge features + attention, pk-bf16 atomics
//   k4: h2 = agg(bf16)/den(bf16) + skip; log_softmax(h2 @ Wout + bout)

#define FIN 172
#define INV_SQRT_C 0.25f

typedef _Float16 f16x8 __attribute__((ext_vector_type(8)));
typedef float f32x4 __attribute__((ext_vector_type(4)));

__device__ __forceinline__ uint32_t cvt_pk_bf16(float lo, float hi) {
    uint32_t r;
    asm("v_cvt_pk_bf16_f32 %0, %1, %2" : "=v"(r) : "v"(lo), "v"(hi));
    return r;
}
__device__ __forceinline__ float bflo(uint32_t u) {
    union { uint32_t i; float f; } x; x.i = u << 16; return x.f;
}
__device__ __forceinline__ float bfhi(uint32_t u) {
    union { uint32_t i; float f; } x; x.i = u & 0xFFFF0000u; return x.f;
}
__device__ __forceinline__ void pk_atomic_add_bf16(void* addr, uint32_t data) {
    asm volatile("global_atomic_pk_add_bf16 %0, %1, off"
                 :: "v"((uint64_t)(uintptr_t)addr), "v"(data) : "memory");
}

// ---------------------------------------------------------------------------
// k1: h1pre = x @ Wlin + blin. 256 thr = 8 rows x 32 cols, 2 rows/thread.
// ---------------------------------------------------------------------------
__global__ __launch_bounds__(256) void k1_lin(
    const float* __restrict__ x, const float* __restrict__ Wlin,
    const float* __restrict__ blin, float* __restrict__ h1pre, int n)
{
    __shared__ __align__(16) float WlT[32][174];
    __shared__ __align__(16) float xs[16][FIN];
    const int t = threadIdx.x;

    for (int i = t; i < FIN * 32; i += 256) {
        int kk = i >> 5, o = i & 31;
        WlT[o][kk] = Wlin[i];
    }
    const int row0 = blockIdx.x * 16;
    for (int i = t; i < 16 * FIN; i += 256) {
        int rr = i / FIN, kk = i - rr * FIN;
        int gr = row0 + rr;
        xs[rr][kk] = (gr < n) ? x[(size_t)gr * FIN + kk] : 0.f;
    }
    __syncthreads();

    const int o = t & 31, r = t >> 5;
    float acc0 = blin[o], acc1 = acc0;
    const float2* wp  = reinterpret_cast<const float2*>(&WlT[o][0]);
    const float2* xp0 = reinterpret_cast<const float2*>(&xs[r][0]);
    const float2* xp1 = reinterpret_cast<const float2*>(&xs[r + 8][0]);
    #pragma unroll 4
    for (int kk = 0; kk < FIN / 2; ++kk) {
        float2 wv = wp[kk], xa = xp0[kk], xb = xp1[kk];
        acc0 = fmaf(xa.x, wv.x, acc0);
        acc0 = fmaf(xa.y, wv.y, acc0);
        acc1 = fmaf(xb.x, wv.x, acc1);
        acc1 = fmaf(xb.y, wv.y, acc1);
    }
    const int g0 = row0 + r, g1 = row0 + r + 8;
    if (g0 < n) h1pre[(size_t)g0 * 32 + o] = acc0;
    if (g1 < n) h1pre[(size_t)g1 * 32 + o] = acc1;
}

// ---------------------------------------------------------------------------
template <int K, int O>
__device__ __forceinline__ void matvecKO(const float* __restrict__ v,
                                         const float* __restrict__ W,
                                         const float* __restrict__ B,
                                         float* __restrict__ out)
{
    #pragma unroll
    for (int o4 = 0; o4 < O / 4; ++o4) {
        float a0 = B[o4 * 4 + 0], a1 = B[o4 * 4 + 1];
        float a2 = B[o4 * 4 + 2], a3 = B[o4 * 4 + 3];
        #pragma unroll
        for (int k = 0; k < K; ++k) {
            float4 wv = *reinterpret_cast<const float4*>(&W[k * O + o4 * 4]);
            float hv = v[k];
            a0 = fmaf(hv, wv.x, a0);
            a1 = fmaf(hv, wv.y, a1);
            a2 = fmaf(hv, wv.z, a2);
            a3 = fmaf(hv, wv.w, a3);
        }
        out[o4 * 4 + 0] = a0; out[o4 * 4 + 1] = a1;
        out[o4 * 4 + 2] = a2; out[o4 * 4 + 3] = a3;
    }
}

__device__ __forceinline__ void store32(float* __restrict__ dst,
                                        const float* __restrict__ v)
{
    float4* d4 = reinterpret_cast<float4*>(dst);
    #pragma unroll
    for (int i = 0; i < 8; ++i)
        d4[i] = make_float4(v[4 * i], v[4 * i + 1], v[4 * i + 2], v[4 * i + 3]);
}

// ---------------------------------------------------------------------------
// k2: per-node encoder + combine + projections.
// q32[n][16]: m -> pk(q_m, q_{16+m});  kv32[n][32]: 2m -> pk(k_m,k_{16+m}),
//                                                   2m+1 -> pk(v_m,v_{16+m})
// ---------------------------------------------------------------------------
__global__ __launch_bounds__(256) void k2_enc(
    const float* __restrict__ h1pre,
    const float* __restrict__ node_interval, const float* __restrict__ node_degree,
    const float* __restrict__ Wtf, const float* __restrict__ btf,
    const float* __restrict__ Wd,  const float* __restrict__ bd,
    const float* __restrict__ Wenc, const float* __restrict__ benc,
    const float* __restrict__ Wx,  const float* __restrict__ bx,
    const float* __restrict__ Wcomb, const float* __restrict__ bcomb,
    const float* __restrict__ Wq,  const float* __restrict__ bq,
    const float* __restrict__ Wk,  const float* __restrict__ bk,
    const float* __restrict__ Wv,  const float* __restrict__ bv,
    const float* __restrict__ Wskip, const float* __restrict__ bskip,
    uint32_t* __restrict__ q32, uint32_t* __restrict__ kv32,
    float* __restrict__ skipb, int n)
{
    __shared__ __align__(16) float sWenc[64], sWx[256], sWcomb[1280];
    __shared__ __align__(16) float sWq[1024], sWk[1024], sWv[1024], sWs[1024];
    __shared__ float sWtf[8], sbtf[8], sWd[8], sbd[8], sbenc[8], sbx[8];
    __shared__ float sbcomb[32], sbq[32], sbk[32], sbv[32], sbs[32];

    const int t = threadIdx.x;
    if (t < 8) {
        sWtf[t] = Wtf[t]; sbtf[t] = btf[t];
        sWd[t]  = Wd[t];  sbd[t]  = bd[t];
        sbenc[t] = benc[t]; sbx[t] = bx[t];
    }
    if (t < 32) {
        sbcomb[t] = bcomb[t]; sbq[t] = bq[t]; sbk[t] = bk[t];
        sbv[t] = bv[t]; sbs[t] = bskip[t];
    }
    if (t < 64) sWenc[t] = Wenc[t];
    if (t < 256) sWx[t] = Wx[t];
    for (int i = t; i < 1280; i += 256) sWcomb[i] = Wcomb[i];
    for (int i = t; i < 1024; i += 256) {
        sWq[i] = Wq[i]; sWk[i] = Wk[i]; sWv[i] = Wv[i]; sWs[i] = Wskip[i];
    }
    __syncthreads();

    const int nid = blockIdx.x * 256 + t;
    if (nid >= n) return;

    float h1p[32];
    {
        const float2* hp = reinterpret_cast<const float2*>(h1pre + (size_t)nid * 32);
        #pragma unroll
        for (int i = 0; i < 16; ++i) {
            float2 v2 = hp[i];
            h1p[2 * i] = v2.x; h1p[2 * i + 1] = v2.y;
        }
    }
    const float ti = node_interval[nid], dg = node_degree[nid];
    float tf[8], de[8];
    #pragma unroll
    for (int j = 0; j < 8; ++j) {
        tf[j] = fmaf(ti, sWtf[j], sbtf[j]);
        de[j] = fmaf(dg, sWd[j], sbd[j]);
    }
    float xp[8];
    matvecKO<32, 8>(h1p, sWx, sbx, xp);
    #pragma unroll
    for (int o = 0; o < 8; ++o) xp[o] = tanhf(xp[o]);

    float ep0[8], ep1[8];
    matvecKO<8, 8>(tf, sWenc, sbenc, ep0);
    matvecKO<8, 8>(de, sWenc, sbenc, ep1);
    float sc0 = 0.f, sc1 = 0.f;
    #pragma unroll
    for (int o = 0; o < 8; ++o) {
        sc0 = fmaf(tanhf(ep0[o]), xp[o], sc0);
        sc1 = fmaf(tanhf(ep1[o]), xp[o], sc1);
    }
    const float mm = fmaxf(sc0, sc1);
    const float e0 = __expf(sc0 - mm), e1 = __expf(sc1 - mm);
    const float inv = 1.f / (e0 + e1);
    const float s0 = e0 * inv, s1 = e1 * inv;

    float v40[40];
    #pragma unroll
    for (int i = 0; i < 32; ++i) v40[i] = h1p[i];
    #pragma unroll
    for (int j = 0; j < 8; ++j) v40[32 + j] = fmaf(s0, tf[j], s1 * de[j]);
    float h1[32];
    matvecKO<40, 32>(v40, sWcomb, sbcomb, h1);

    float tq[32], tk[32], tv[32], ts[32];
    matvecKO<32, 32>(h1, sWq, sbq, tq);
    matvecKO<32, 32>(h1, sWk, sbk, tk);
    matvecKO<32, 32>(h1, sWv, sbv, tv);
    matvecKO<32, 32>(h1, sWs, sbs, ts);

    uint32_t* qw  = q32  + (size_t)nid * 16;
    uint32_t* kvw = kv32 + (size_t)nid * 32;
    #pragma unroll
    for (int p = 0; p < 16; ++p) {
        qw[p]          = cvt_pk_bf16(tq[p], tq[16 + p]);
        kvw[2 * p]     = cvt_pk_bf16(tk[p], tk[16 + p]);
        kvw[2 * p + 1] = cvt_pk_bf16(tv[p], tv[16 + p]);
    }
    store32(skipb + (size_t)nid * 32, ts);
}

// ---------------------------------------------------------------------------
// k3: edge kernel, latency-pipelined. One wave = one 16-edge tile.
// Per tile: (1) stage-1 (ei/edge_time) was prefetched last iteration;
// (2) issue node_time[src] + ALL q/kv gathers (addresses via shfl of ei) +
// next tile's stage-1, all overlapping; (3) cos -> 2x MFMA; (4) per-r
// combine/reduce/exp -> 16 pk agg atomics + 1 pk den atomic.
// ---------------------------------------------------------------------------
__global__ __launch_bounds__(256) void k3_edge(
    const int* __restrict__ ei, const float* __restrict__ node_time,
    const float* __restrict__ edge_time,
    const uint32_t* __restrict__ qp, const uint32_t* __restrict__ kvp,
    const float* __restrict__ Wt, const float* __restrict__ bt,
    const float* __restrict__ We, const float* __restrict__ be,
    unsigned short* __restrict__ agg, unsigned short* __restrict__ den,
    int numE, int nTiles)
{
    const int lane = threadIdx.x & 63;
    const int g = lane >> 4;          // k-group / C row group
    const int m = lane & 15;          // A row (edge-in-tile) / B,C column

    float wtr[8], btr[8];
    f16x8 B0, B1;
    #pragma unroll
    for (int i = 0; i < 8; ++i) {
        const int k = g * 8 + i;
        wtr[i] = Wt[k];
        btr[i] = bt[k];
        B0[i] = (_Float16)We[k * 32 + m];
        B1[i] = (_Float16)We[k * 32 + 16 + m];
    }
    const float be0 = be[m], be1 = be[16 + m];

    const int wid = blockIdx.x * (blockDim.x >> 6) + (threadIdx.x >> 6);
    const int nW  = gridDim.x * (blockDim.x >> 6);

    int tile = wid;
    if (tile >= nTiles) return;

    // stage-1 prologue for the first tile
    int srcm = 0, dstm = 0;
    float et = 0.f;
    {
        const int eA = tile * 16 + m;
        if (eA < numE) {
            srcm = ei[eA];
            dstm = ei[numE + eA];
            et   = edge_time[eA];
        }
    }

    while (true) {
        // ---- issue all gathers for this tile ----
        const float nt = node_time[srcm];              // dep: srcm only
        int srcr[4], dstr[4];
        uint32_t qw[4];
        uint2 kvw[4];
        #pragma unroll
        for (int r = 0; r < 4; ++r) {
            const int j = g * 4 + r;
            srcr[r] = __shfl(srcm, j);
            dstr[r] = __shfl(dstm, j);
            qw[r]  = qp[(size_t)dstr[r] * 16 + m];     // 4B: (q_m, q_16+m)
            kvw[r] = *reinterpret_cast<const uint2*>(  // 8B: (k pair, v pair)
                         kvp + (size_t)srcr[r] * 32 + 2 * m);
        }

        // ---- prefetch next tile's stage-1 ----
        const int ntile = tile + nW;
        int nsrc = 0, ndst = 0;
        float net = 0.f;
        if (ntile < nTiles) {
            const int eA = ntile * 16 + m;
            if (eA < numE) {
                nsrc = ei[eA];
                ndst = ei[numE + eA];
                net  = edge_time[eA];
            }
        }

        // ---- edge features: cos + 2x MFMA ----
        const float rel = nt - et;
        f16x8 A;
        #pragma unroll
        for (int i = 0; i < 8; ++i)
            A[i] = (_Float16)__cosf(fmaf(rel, wtr[i], btr[i]));

        f32x4 acc0 = {0.f, 0.f, 0.f, 0.f};
        f32x4 acc1 = {0.f, 0.f, 0.f, 0.f};
        acc0 = __builtin_amdgcn_mfma_f32_16x16x32_f16(A, B0, acc0, 0, 0, 0);
        acc1 = __builtin_amdgcn_mfma_f32_16x16x32_f16(A, B1, acc1, 0, 0, 0);

        const int e0 = tile * 16;
        #pragma unroll
        for (int r = 0; r < 4; ++r) {
            if (e0 + g * 4 + r < numE) {
                const float ef0 = acc0[r] + be0;       // channel m      (head 0)
                const float ef1 = acc1[r] + be1;       // channel 16+m   (head 1)

                const uint32_t uq = qw[r];
                const uint32_t uk = kvw[r].x, uv = kvw[r].y;
                const float q0 = bflo(uq), q1 = bfhi(uq);
                const float k0 = bflo(uk), k1 = bfhi(uk);
                const float v0 = bflo(uv), v1 = bfhi(uv);

                float p0 = q0 * (k0 + ef0);
                float p1 = q1 * (k1 + ef1);
                #pragma unroll
                for (int s = 1; s < 16; s <<= 1) {
                    p0 += __shfl_xor(p0, s);
                    p1 += __shfl_xor(p1, s);
                }
                const float w0 = __expf(p0 * INV_SQRT_C);
                const float w1 = __expf(p1 * INV_SQRT_C);

                const float t0 = w0 * (v0 + ef0);
                const float t1 = w1 * (v1 + ef1);
                const float x0 = __shfl_xor(t0, 1);
                const float x1 = __shfl_xor(t1, 1);
                const uint32_t data = (m & 1) ? cvt_pk_bf16(x1, t1)
                                              : cvt_pk_bf16(t0, x0);
                const int choff = (m & 1) ? (15 + m) : m;
                pk_atomic_add_bf16(agg + (size_t)dstr[r] * 32 + choff, data);

                if (m == 0)
                    pk_atomic_add_bf16(den + (size_t)dstr[r] * 2,
                                       cvt_pk_bf16(w0, w1));
            }
        }

        if (ntile >= nTiles) break;
        tile = ntile; srcm = nsrc; dstm = ndst; et = net;
    }
}

// ---------------------------------------------------------------------------
// k4: h2 = agg(bf16)/den(bf16) + skip; out = log_softmax(h2 @ Wout + bout).
// ---------------------------------------------------------------------------
__global__ __launch_bounds__(256) void k4_out(
    const unsigned short* __restrict__ agg, const unsigned short* __restrict__ den,
    const float* __restrict__ skipb,
    const float* __restrict__ Wout, const float* __restrict__ bout,
    float* __restrict__ out, int n)
{
    __shared__ float sW[64];
    __shared__ float sb[2];
    const int t = threadIdx.x;
    if (t < 64) sW[t] = Wout[t];
    if (t < 2) sb[t] = bout[t];
    __syncthreads();

    const int nid = blockIdx.x * 256 + t;
    if (nid >= n) return;

    const uint32_t ud = reinterpret_cast<const uint32_t*>(den)[nid];
    const float inv0 = 1.f / (bflo(ud) + 1e-16f);
    const float inv1 = 1.f / (bfhi(ud) + 1e-16f);
    const uint32_t* ag = reinterpret_cast<const uint32_t*>(agg) + (size_t)nid * 16;
    const float*    sk = skipb + (size_t)nid * 32;

    float o0 = sb[0], o1 = sb[1];
    #pragma unroll
    for (int p = 0; p < 16; ++p) {                 // channel pair (2p, 2p+1)
        const uint32_t u = ag[p];
        const float iv = (p < 8) ? inv0 : inv1;
        const float hLo = fmaf(bflo(u), iv, sk[2 * p]);
        const float hHi = fmaf(bfhi(u), iv, sk[2 * p + 1]);
        o0 = fmaf(hLo, sW[(2 * p) * 2],     o0);
        o1 = fmaf(hLo, sW[(2 * p) * 2 + 1], o1);
        o0 = fmaf(hHi, sW[(2 * p + 1) * 2],     o0);
        o1 = fmaf(hHi, sW[(2 * p + 1) * 2 + 1], o1);
    }
    const float mm = fmaxf(o0, o1);
    const float lse = mm + __logf(__expf(o0 - mm) + __expf(o1 - mm));
    out[(size_t)nid * 2 + 0] = o0 - lse;
    out[(size_t)nid * 2 + 1] = o1 - lse;
}

// ---------------------------------------------------------------------------
extern "C" void kernel_launch(void* const* d_in, const int* in_sizes, int n_in,
                              void* d_out, int out_size, void* d_ws, size_t ws_size,
                              hipStream_t stream)
{
    const float* x             = (const float*)d_in[0];
    const int*   ei            = (const int*)  d_in[1];
    const float* node_time     = (const float*)d_in[2];
    const float* edge_time     = (const float*)d_in[3];
    const float* node_interval = (const float*)d_in[4];
    const float* node_degree   = (const float*)d_in[5];
    const float* Wt    = (const float*)d_in[6];  const float* bt    = (const float*)d_in[7];
    const float* Wd    = (const float*)d_in[8];  const float* bd    = (const float*)d_in[9];
    const float* Wtf   = (const float*)d_in[10]; const float* btf   = (const float*)d_in[11];
    const float* Wenc  = (const float*)d_in[12]; const float* benc  = (const float*)d_in[13];
    const float* Wx    = (const float*)d_in[14]; const float* bx    = (const float*)d_in[15];
    const float* Wlin  = (const float*)d_in[16]; const float* blin  = (const float*)d_in[17];
    const float* Wcomb = (const float*)d_in[18]; const float* bcomb = (const float*)d_in[19];
    const float* Wq    = (const float*)d_in[20]; const float* bq    = (const float*)d_in[21];
    const float* Wk    = (const float*)d_in[22]; const float* bk    = (const float*)d_in[23];
    const float* Wv    = (const float*)d_in[24]; const float* bv    = (const float*)d_in[25];
    const float* We    = (const float*)d_in[26]; const float* be    = (const float*)d_in[27];
    const float* Wskip = (const float*)d_in[28]; const float* bskip = (const float*)d_in[29];
    const float* Wout  = (const float*)d_in[30]; const float* bout  = (const float*)d_in[31];

    const int n    = in_sizes[2];   // node_time: [N]
    const int numE = in_sizes[3];   // edge_time: [E,1]

    // ---- workspace carve (bytes) ----
    char* base = (char*)d_ws;
    uint32_t* q32  = (uint32_t*)base; base += (size_t)n * 16 * 4;   // q pairs
    uint32_t* kv32 = (uint32_t*)base; base += (size_t)n * 32 * 4;   // kv quads
    float* skipb = (float*)base; base += (size_t)n * 32 * 4;
    float* h1pre = (float*)base; base += (size_t)n * 32 * 4;
    unsigned short* agg = (unsigned short*)base; base += (size_t)n * 32 * 2;
    unsigned short* den = (unsigned short*)base; base += (size_t)n * 2 * 2;

    // zero the atomic accumulators (agg bf16 + den bf16, contiguous)
    hipMemsetAsync(agg, 0, (size_t)n * (32 * 2 + 2 * 2), stream);

    k1_lin<<<(n + 15) / 16, 256, 0, stream>>>(x, Wlin, blin, h1pre, n);

    k2_enc<<<(n + 255) / 256, 256, 0, stream>>>(
        h1pre, node_interval, node_degree,
        Wtf, btf, Wd, bd, Wenc, benc, Wx, bx, Wcomb, bcomb,
        Wq, bq, Wk, bk, Wv, bv, Wskip, bskip,
        q32, kv32, skipb, n);

    const int nTiles = (numE + 15) / 16;
    k3_edge<<<4096, 256, 0, stream>>>(
        ei, node_time, edge_time, q32, kv32,
        Wt, bt, We, be, agg, den, numE, nTiles);

    k4_out<<<(n + 255) / 256, 256, 0, stream>>>(
        agg, den, skipb, Wout, bout, (float*)d_out, n);
}